// Round 17
// baseline (126.239 us; speedup 1.0000x reference)
//
#include <hip/hip_runtime.h>
#include <hip/hip_bf16.h>

#define B_   16
#define NC_  1024
#define NQ_  128
#define D_   512
#define NKT  8        // K-tiles: 512/64

typedef __attribute__((ext_vector_type(8))) short bf16x8;
typedef __attribute__((ext_vector_type(4))) float f32x4;

// fp32 -> bf16 RTNE
__device__ __forceinline__ short f2bf(float x) {
    return __builtin_bit_cast(short, __float2bfloat16(x));
}
// bf16 -> fp32 (exact)
__device__ __forceinline__ float bf2f(short s) {
    unsigned u = ((unsigned)(unsigned short)s) << 16;
    return __builtin_bit_cast(float, u);
}

// R17 PROBE: R13's verified fused kernel (16.36us), K-pipeline repeated REPS
// times (acc and side-sums scale by 1/REPS — exact for 16). Purpose:
// (a) hot per-pass = (dur_R17 - 16.36)/15; (b) direct counters on the fused
// structure (VALUBusy vs MfmaUtil vs latency signature) to pick the R18 lever.
template <int REPS>
__global__ __launch_bounds__(256, 2) void sim_kernel(
    const float* __restrict__ c, const float* __restrict__ q,
    const float* __restrict__ kern, const float* __restrict__ bias_p,
    float* __restrict__ out)
{
    __shared__ __align__(16) char  lds[2][16384];  // per buf: A bf16[64][64] | B bf16[64][64]
    __shared__ __align__(16) short wl[1536];       // bf16: [0,512) w_c | [512,1024) w_q | [1024,1536) w_cq
    __shared__ __align__(16) float ctl[64];
    __shared__ __align__(16) float qtl[64];

    const int bid   = blockIdx.x;
    const int b     = ((bid & 7) << 1) | (bid >> 8);   // XCD-affine batch (bijective)
    const int inner = (bid >> 3) & 31;
    const int mt    = inner >> 1;                      // 16 M-tiles of 64 rows
    const int nb    = inner & 1;                       // 2 N-halves of 64 cols
    const int tid   = threadIdx.x;
    const int lane  = tid & 63;
    const int w     = tid >> 6;
    const int wm    = w >> 1, wn = w & 1;              // 2x2 wave grid
    const int rif   = lane & 15;
    const int kg    = lane >> 4;

    // ---- weights -> LDS bf16 (once; 192 threads x 8) ----
    if (tid < 192) {
        const float* s = kern + tid * 8;
        f32x4 v0 = *(const f32x4*)s;
        f32x4 v1 = *(const f32x4*)(s + 4);
        bf16x8 o;
        o[0]=f2bf(v0[0]); o[1]=f2bf(v0[1]); o[2]=f2bf(v0[2]); o[3]=f2bf(v0[3]);
        o[4]=f2bf(v1[0]); o[5]=f2bf(v1[1]); o[6]=f2bf(v1[2]); o[7]=f2bf(v1[3]);
        *(bf16x8*)&wl[tid * 8] = o;
    }

    const int ar0 = tid >> 3, ar1 = ar0 + 32;
    const int acs = (tid & 7) * 8;
    const float* ag0 = c + (size_t)(b * NC_ + mt * 64 + ar0) * D_ + acs;
    const float* ag1 = c + (size_t)(b * NC_ + mt * 64 + ar1) * D_ + acs;
    const int aw0 = ar0 * 128 + ((acs * 2) ^ ((ar0 & 7) << 4));
    const int aw1 = ar1 * 128 + ((acs * 2) ^ ((ar1 & 7) << 4));

    const int bj = tid >> 2, bp = tid & 3;
    const float* bg = q + (size_t)(b * NQ_ + nb * 64 + bj) * D_ + bp * 16;
    const int bw0 = 8192 + bj * 128 + ((bp * 32)      ^ ((bj & 7) << 4));
    const int bw1 = 8192 + bj * 128 + ((bp * 32 + 16) ^ ((bj & 7) << 4));

    f32x4 sa[2][4], sb[2][4];
    float ct0 = 0.f, ct1 = 0.f, qta = 0.f;
    f32x4 acc00 = {}, acc01 = {}, acc10 = {}, acc11 = {};

#define ISSUE(T)                                                   \
    do { const int s_ = (T) & 1;                                   \
        sa[s_][0] = *(const f32x4*)(ag0 + (T) * 64);               \
        sa[s_][1] = *(const f32x4*)(ag0 + (T) * 64 + 4);           \
        sa[s_][2] = *(const f32x4*)(ag1 + (T) * 64);               \
        sa[s_][3] = *(const f32x4*)(ag1 + (T) * 64 + 4);           \
        sb[s_][0] = *(const f32x4*)(bg + (T) * 64);                \
        sb[s_][1] = *(const f32x4*)(bg + (T) * 64 + 4);            \
        sb[s_][2] = *(const f32x4*)(bg + (T) * 64 + 8);            \
        sb[s_][3] = *(const f32x4*)(bg + (T) * 64 + 12);           \
    } while (0)

#define WRITE(T)                                                               \
    do { const int s_ = (T) & 1; char* Lw = &lds[s_][0];                       \
        bf16x8 wcq = *(const bf16x8*)&wl[1024 + (T) * 64 + acs];               \
        bf16x8 wc8 = *(const bf16x8*)&wl[       (T) * 64 + acs];               \
        bf16x8 wq0 = *(const bf16x8*)&wl[512  + (T) * 64 + bp * 16];           \
        bf16x8 wq1 = *(const bf16x8*)&wl[512  + (T) * 64 + bp * 16 + 8];       \
        bf16x8 oa0, oa1, ob0, ob1;                                             \
        _Pragma("unroll")                                                      \
        for (int e = 0; e < 8; ++e) {                                          \
            float wcqf = bf2f(wcq[e]);                                         \
            float x0 = sa[s_][e >> 2][e & 3];                                  \
            float x1 = sa[s_][2 + (e >> 2)][e & 3];                            \
            oa0[e] = f2bf(x0 * wcqf);                                          \
            oa1[e] = f2bf(x1 * wcqf);                                          \
            float wcf = bf2f(wc8[e]);                                          \
            ct0 += x0 * wcf;  ct1 += x1 * wcf;                                 \
            float y0 = sb[s_][e >> 2][e & 3];                                  \
            float y1 = sb[s_][2 + (e >> 2)][e & 3];                            \
            ob0[e] = f2bf(y0); ob1[e] = f2bf(y1);                              \
            qta += y0 * bf2f(wq0[e]) + y1 * bf2f(wq1[e]);                      \
        }                                                                      \
        *(bf16x8*)(Lw + aw0) = oa0;                                            \
        *(bf16x8*)(Lw + aw1) = oa1;                                            \
        *(bf16x8*)(Lw + bw0) = ob0;                                            \
        *(bf16x8*)(Lw + bw1) = ob1;                                            \
    } while (0)

#define COMPUTE(T)                                                                                   \
    do { const char* L = &lds[(T) & 1][0];                                                           \
        _Pragma("unroll")                                                                            \
        for (int kk = 0; kk < 2; ++kk) {                                                             \
            const int ks = kk * 64 + kg * 16;                                                        \
            bf16x8 af0, af1, bf0, bf1;                                                               \
            { int r = wm*32 + rif;      af0 = *(const bf16x8*)(L + r*128 + (ks ^ ((r & 7) << 4))); } \
            { int r = wm*32 + 16 + rif; af1 = *(const bf16x8*)(L + r*128 + (ks ^ ((r & 7) << 4))); } \
            { int j = wn*32 + rif;      bf0 = *(const bf16x8*)(L + 8192 + j*128 + (ks ^ ((j & 7) << 4))); } \
            { int j = wn*32 + 16 + rif; bf1 = *(const bf16x8*)(L + 8192 + j*128 + (ks ^ ((j & 7) << 4))); } \
            acc00 = __builtin_amdgcn_mfma_f32_16x16x32_bf16(af0, bf0, acc00, 0, 0, 0);               \
            acc01 = __builtin_amdgcn_mfma_f32_16x16x32_bf16(af0, bf1, acc01, 0, 0, 0);               \
            acc10 = __builtin_amdgcn_mfma_f32_16x16x32_bf16(af1, bf0, acc10, 0, 0, 0);               \
            acc11 = __builtin_amdgcn_mfma_f32_16x16x32_bf16(af1, bf1, acc11, 0, 0, 0);               \
        }                                                                                            \
    } while (0)

    #pragma unroll 1
    for (int rep = 0; rep < REPS; ++rep) {
        asm volatile("" ::: "memory");   // defeat cross-rep CSE/LICM

        // ---- prologue (per pass, as in R13) ----
        ISSUE(0); ISSUE(1);
        asm volatile("s_waitcnt lgkmcnt(0)" ::: "memory");
        __builtin_amdgcn_sched_barrier(0);
        __builtin_amdgcn_s_barrier();
        WRITE(0);
        asm volatile("s_waitcnt lgkmcnt(0)" ::: "memory");
        __builtin_amdgcn_sched_barrier(0);
        __builtin_amdgcn_s_barrier();

        #pragma unroll
        for (int kt = 0; kt < NKT; ++kt) {
            if (kt + 2 < NKT) ISSUE(kt + 2);
            __builtin_amdgcn_sched_barrier(0);
            COMPUTE(kt);
            if (kt + 1 < NKT) {
                WRITE(kt + 1);
                asm volatile("s_waitcnt lgkmcnt(0)" ::: "memory");
                __builtin_amdgcn_sched_barrier(0);
                __builtin_amdgcn_s_barrier();
            }
        }
        __builtin_amdgcn_s_barrier();    // rep boundary: buf reuse safe
    }
#undef ISSUE
#undef WRITE
#undef COMPUTE

    const float inv = 1.0f / (float)REPS;   // exact for 16
    ct0 *= inv; ct1 *= inv; qta *= inv;

    // ---- side-term reductions ----
    ct0 += __shfl_xor(ct0, 1); ct0 += __shfl_xor(ct0, 2); ct0 += __shfl_xor(ct0, 4);
    ct1 += __shfl_xor(ct1, 1); ct1 += __shfl_xor(ct1, 2); ct1 += __shfl_xor(ct1, 4);
    qta += __shfl_xor(qta, 1); qta += __shfl_xor(qta, 2);
    if ((tid & 7) == 0) { ctl[ar0] = ct0; ctl[ar1] = ct1; }
    if ((tid & 3) == 0) qtl[bj] = qta;
    asm volatile("s_waitcnt lgkmcnt(0)" ::: "memory");
    __builtin_amdgcn_sched_barrier(0);
    __builtin_amdgcn_s_barrier();

    // ---- epilogue ----
    const float bias = *bias_p;
    const int jc = wn * 32;
    const float qt0 = qtl[jc + rif]      + bias;
    const float qt1 = qtl[jc + 16 + rif] + bias;
    #pragma unroll
    for (int mf = 0; mf < 2; ++mf) {
        f32x4 ctv = *(const f32x4*)&ctl[wm * 32 + mf * 16 + kg * 4];
        float* o = out + ((size_t)(b * NC_ + mt * 64 + wm * 32 + mf * 16 + kg * 4)) * NQ_
                 + nb * 64 + jc + rif;
        const f32x4 a0 = mf ? acc10 : acc00;
        const f32x4 a1 = mf ? acc11 : acc01;
        #pragma unroll
        for (int r = 0; r < 4; ++r) {
            o[(size_t)r * NQ_ +  0] = a0[r] * inv + ctv[r] + qt0;
            o[(size_t)r * NQ_ + 16] = a1[r] * inv + ctv[r] + qt1;
        }
    }
}

extern "C" void kernel_launch(void* const* d_in, const int* in_sizes, int n_in,
                              void* d_out, int out_size, void* d_ws, size_t ws_size,
                              hipStream_t stream) {
    const float* c    = (const float*)d_in[0];
    const float* q    = (const float*)d_in[1];
    const float* kern = (const float*)d_in[2];
    const float* bias = (const float*)d_in[3];
    float* out = (float*)d_out;

    sim_kernel<16><<<512, 256, 0, stream>>>(c, q, kern, bias, out);
}

// Round 18
// 16.046 us; speedup vs baseline: 7.8675x; 7.8675x over previous
//
#include <hip/hip_runtime.h>
#include <hip/hip_bf16.h>

#define B_   16
#define NC_  1024
#define NQ_  128
#define D_   512
#define NKT  8        // K-tiles: 512/64

typedef __attribute__((ext_vector_type(8))) short bf16x8;
typedef __attribute__((ext_vector_type(4))) float f32x4;

// fp32 -> bf16 RTNE
__device__ __forceinline__ short f2bf(float x) {
    return __builtin_bit_cast(short, __float2bfloat16(x));
}
// bf16 -> fp32 (exact)
__device__ __forceinline__ float bf2f(short s) {
    unsigned u = ((unsigned)(unsigned short)s) << 16;
    return __builtin_bit_cast(float, u);
}

// R18: R13 verbatim except ONE change (per R17 probe: VALUBusy 40% -> WRITE is
// VALU-bound): qt_j moves from VALU side-sum to broadcast-MFMA on the RAW B.
//  A = bf16(c * w_cq) (fold on A, R13-verified); B = bf16(q) (raw);
//  ct_i = VALU side-sum on raw staged A (R13-verified);
//  qt_j = mfma(wq_bcast, bf): D[i][j] = qt_j for all i (valid: B is raw).
// Removes 16 FMA + 2 LDS weight reads per thread per kt from WRITE (-25% VALU);
// adds 4 MFMAs/wave/kt on the 10%-utilized matrix pipe.
__global__ __launch_bounds__(256, 2) void sim_kernel(
    const float* __restrict__ c, const float* __restrict__ q,
    const float* __restrict__ kern, const float* __restrict__ bias_p,
    float* __restrict__ out)
{
    __shared__ __align__(16) char  lds[2][16384];  // per buf: A bf16[64][64] | B bf16[64][64]
    __shared__ __align__(16) short wl[1536];       // bf16: [0,512) w_c | [512,1024) w_q | [1024,1536) w_cq
    __shared__ __align__(16) float ctl[64];

    const int bid   = blockIdx.x;
    const int b     = ((bid & 7) << 1) | (bid >> 8);   // XCD-affine batch (bijective)
    const int inner = (bid >> 3) & 31;
    const int mt    = inner >> 1;                      // 16 M-tiles of 64 rows
    const int nb    = inner & 1;                       // 2 N-halves of 64 cols
    const int tid   = threadIdx.x;
    const int lane  = tid & 63;
    const int w     = tid >> 6;
    const int wm    = w >> 1, wn = w & 1;              // 2x2 wave grid
    const int rif   = lane & 15;
    const int kg    = lane >> 4;

    // ---- weights -> LDS bf16 (once; 192 threads x 8) ----
    if (tid < 192) {
        const float* s = kern + tid * 8;
        f32x4 v0 = *(const f32x4*)s;
        f32x4 v1 = *(const f32x4*)(s + 4);
        bf16x8 o;
        o[0]=f2bf(v0[0]); o[1]=f2bf(v0[1]); o[2]=f2bf(v0[2]); o[3]=f2bf(v0[3]);
        o[4]=f2bf(v1[0]); o[5]=f2bf(v1[1]); o[6]=f2bf(v1[2]); o[7]=f2bf(v1[3]);
        *(bf16x8*)&wl[tid * 8] = o;
    }

    const int ar0 = tid >> 3, ar1 = ar0 + 32;
    const int acs = (tid & 7) * 8;
    const float* ag0 = c + (size_t)(b * NC_ + mt * 64 + ar0) * D_ + acs;
    const float* ag1 = c + (size_t)(b * NC_ + mt * 64 + ar1) * D_ + acs;
    const int aw0 = ar0 * 128 + ((acs * 2) ^ ((ar0 & 7) << 4));
    const int aw1 = ar1 * 128 + ((acs * 2) ^ ((ar1 & 7) << 4));

    const int bj = tid >> 2, bp = tid & 3;
    const float* bg = q + (size_t)(b * NQ_ + nb * 64 + bj) * D_ + bp * 16;
    const int bw0 = 8192 + bj * 128 + ((bp * 32)      ^ ((bj & 7) << 4));
    const int bw1 = 8192 + bj * 128 + ((bp * 32 + 16) ^ ((bj & 7) << 4));

    f32x4 sa[2][4], sb[2][4];
    float ct0 = 0.f, ct1 = 0.f;
    f32x4 acc00 = {}, acc01 = {}, acc10 = {}, acc11 = {};
    f32x4 acc_q0 = {}, acc_q1 = {};    // D[i][j] = qt_j (broadcast-A MFMA on raw B)

#define ISSUE(T)                                                   \
    do { const int s_ = (T) & 1;                                   \
        sa[s_][0] = *(const f32x4*)(ag0 + (T) * 64);               \
        sa[s_][1] = *(const f32x4*)(ag0 + (T) * 64 + 4);           \
        sa[s_][2] = *(const f32x4*)(ag1 + (T) * 64);               \
        sa[s_][3] = *(const f32x4*)(ag1 + (T) * 64 + 4);           \
        sb[s_][0] = *(const f32x4*)(bg + (T) * 64);                \
        sb[s_][1] = *(const f32x4*)(bg + (T) * 64 + 4);            \
        sb[s_][2] = *(const f32x4*)(bg + (T) * 64 + 8);            \
        sb[s_][3] = *(const f32x4*)(bg + (T) * 64 + 12);           \
    } while (0)

#define WRITE(T)                                                               \
    do { const int s_ = (T) & 1; char* Lw = &lds[s_][0];                       \
        bf16x8 wcq = *(const bf16x8*)&wl[1024 + (T) * 64 + acs];               \
        bf16x8 wc8 = *(const bf16x8*)&wl[       (T) * 64 + acs];               \
        bf16x8 oa0, oa1, ob0, ob1;                                             \
        _Pragma("unroll")                                                      \
        for (int e = 0; e < 8; ++e) {                                          \
            float wcqf = bf2f(wcq[e]);                                         \
            float x0 = sa[s_][e >> 2][e & 3];                                  \
            float x1 = sa[s_][2 + (e >> 2)][e & 3];                            \
            oa0[e] = f2bf(x0 * wcqf);                                          \
            oa1[e] = f2bf(x1 * wcqf);                                          \
            float wcf = bf2f(wc8[e]);                                          \
            ct0 += x0 * wcf;  ct1 += x1 * wcf;                                 \
            ob0[e] = f2bf(sb[s_][e >> 2][e & 3]);                              \
            ob1[e] = f2bf(sb[s_][2 + (e >> 2)][e & 3]);                        \
        }                                                                      \
        *(bf16x8*)(Lw + aw0) = oa0;                                            \
        *(bf16x8*)(Lw + aw1) = oa1;                                            \
        *(bf16x8*)(Lw + bw0) = ob0;                                            \
        *(bf16x8*)(Lw + bw1) = ob1;                                            \
    } while (0)

#define COMPUTE(T)                                                                                   \
    do { const char* L = &lds[(T) & 1][0];                                                           \
        _Pragma("unroll")                                                                            \
        for (int kk = 0; kk < 2; ++kk) {                                                             \
            const int ks = kk * 64 + kg * 16;                                                        \
            bf16x8 af0, af1, bf0, bf1, wqf;                                                          \
            { int r = wm*32 + rif;      af0 = *(const bf16x8*)(L + r*128 + (ks ^ ((r & 7) << 4))); } \
            { int r = wm*32 + 16 + rif; af1 = *(const bf16x8*)(L + r*128 + (ks ^ ((r & 7) << 4))); } \
            { int j = wn*32 + rif;      bf0 = *(const bf16x8*)(L + 8192 + j*128 + (ks ^ ((j & 7) << 4))); } \
            { int j = wn*32 + 16 + rif; bf1 = *(const bf16x8*)(L + 8192 + j*128 + (ks ^ ((j & 7) << 4))); } \
            wqf = *(const bf16x8*)&wl[512 + (T) * 64 + kk * 32 + kg * 8];                            \
            acc00 = __builtin_amdgcn_mfma_f32_16x16x32_bf16(af0, bf0, acc00, 0, 0, 0);               \
            acc01 = __builtin_amdgcn_mfma_f32_16x16x32_bf16(af0, bf1, acc01, 0, 0, 0);               \
            acc10 = __builtin_amdgcn_mfma_f32_16x16x32_bf16(af1, bf0, acc10, 0, 0, 0);               \
            acc11 = __builtin_amdgcn_mfma_f32_16x16x32_bf16(af1, bf1, acc11, 0, 0, 0);               \
            acc_q0 = __builtin_amdgcn_mfma_f32_16x16x32_bf16(wqf, bf0, acc_q0, 0, 0, 0);             \
            acc_q1 = __builtin_amdgcn_mfma_f32_16x16x32_bf16(wqf, bf1, acc_q1, 0, 0, 0);             \
        }                                                                                            \
    } while (0)

    // ---- prologue ----
    ISSUE(0); ISSUE(1);
    asm volatile("s_waitcnt lgkmcnt(0)" ::: "memory");
    __builtin_amdgcn_sched_barrier(0);
    __builtin_amdgcn_s_barrier();
    WRITE(0);
    asm volatile("s_waitcnt lgkmcnt(0)" ::: "memory");
    __builtin_amdgcn_sched_barrier(0);
    __builtin_amdgcn_s_barrier();

    #pragma unroll
    for (int kt = 0; kt < NKT; ++kt) {
        if (kt + 2 < NKT) ISSUE(kt + 2);
        __builtin_amdgcn_sched_barrier(0);
        COMPUTE(kt);
        if (kt + 1 < NKT) {
            WRITE(kt + 1);
            asm volatile("s_waitcnt lgkmcnt(0)" ::: "memory");
            __builtin_amdgcn_sched_barrier(0);
            __builtin_amdgcn_s_barrier();
        }
    }
#undef ISSUE
#undef WRITE
#undef COMPUTE

    // ---- ct reduction (VALU side-sum, R13-verified) ----
    ct0 += __shfl_xor(ct0, 1); ct0 += __shfl_xor(ct0, 2); ct0 += __shfl_xor(ct0, 4);
    ct1 += __shfl_xor(ct1, 1); ct1 += __shfl_xor(ct1, 2); ct1 += __shfl_xor(ct1, 4);
    if ((tid & 7) == 0) { ctl[ar0] = ct0; ctl[ar1] = ct1; }
    asm volatile("s_waitcnt lgkmcnt(0)" ::: "memory");
    __builtin_amdgcn_sched_barrier(0);
    __builtin_amdgcn_s_barrier();

    // ---- epilogue: out = cq + ct + qt + bias ----
    const float bias = *bias_p;
    const float qt0 = acc_q0[0] + bias;     // all regs of acc_q equal qt_j (j = wn*32+rif)
    const float qt1 = acc_q1[0] + bias;
    #pragma unroll
    for (int mf = 0; mf < 2; ++mf) {
        f32x4 ctv = *(const f32x4*)&ctl[wm * 32 + mf * 16 + kg * 4];
        float* o = out + ((size_t)(b * NC_ + mt * 64 + wm * 32 + mf * 16 + kg * 4)) * NQ_
                 + nb * 64 + wn * 32 + rif;
        const f32x4 a0 = mf ? acc10 : acc00;
        const f32x4 a1 = mf ? acc11 : acc01;
        #pragma unroll
        for (int r = 0; r < 4; ++r) {
            o[(size_t)r * NQ_ +  0] = a0[r] + ctv[r] + qt0;
            o[(size_t)r * NQ_ + 16] = a1[r] + ctv[r] + qt1;
        }
    }
}

extern "C" void kernel_launch(void* const* d_in, const int* in_sizes, int n_in,
                              void* d_out, int out_size, void* d_ws, size_t ws_size,
                              hipStream_t stream) {
    const float* c    = (const float*)d_in[0];
    const float* q    = (const float*)d_in[1];
    const float* kern = (const float*)d_in[2];
    const float* bias = (const float*)d_in[3];
    float* out = (float*)d_out;

    // Single fused launch: 16 b x 16 mt x 2 nb = 512 blocks (XCD-affine decode in-kernel).
    sim_kernel<<<512, 256, 0, stream>>>(c, q, kern, bias, out);
}

// Round 19
// 15.289 us; speedup vs baseline: 8.2567x; 1.0495x over previous
//
#include <hip/hip_runtime.h>
#include <hip/hip_bf16.h>

#define B_   16
#define NC_  1024
#define NQ_  128
#define D_   512
#define NKT  8        // K-tiles: 512/64

typedef __attribute__((ext_vector_type(8))) short bf16x8;
typedef __attribute__((ext_vector_type(4))) float f32x4;

// fp32 -> bf16 RTNE
__device__ __forceinline__ short f2bf(float x) {
    return __builtin_bit_cast(short, __float2bfloat16(x));
}
// bf16 -> fp32 (exact)
__device__ __forceinline__ float bf2f(short s) {
    unsigned u = ((unsigned)(unsigned short)s) << 16;
    return __builtin_bit_cast(float, u);
}

// R19: R18's verified pipeline + ONE change: 512-thread blocks (8 waves, 2Mx4N,
// wave tile 32x16) on the same 64x64 tile / grid 512.
//  (a) staging per thread halves (1 A-row + 1 B-row slice of 8 floats) -> WRITE
//      VALU per wave halves;  (b) 16 waves/CU (was 8) -> 2x TLP over latency.
//  A = bf16(c*w_cq) fold-on-A; B = bf16(q) raw; ct = VALU side-sum (raw A);
//  qt = broadcast-MFMA on raw B (R18-verified).
// LDS: 2 x (A bf16[64][64] | B bf16[64][64]) + weights 3KB + ctl. ~70 VGPR.
__global__ __launch_bounds__(512, 4) void sim_kernel(
    const float* __restrict__ c, const float* __restrict__ q,
    const float* __restrict__ kern, const float* __restrict__ bias_p,
    float* __restrict__ out)
{
    __shared__ __align__(16) char  lds[2][16384];  // per buf: A@0 | B@8192
    __shared__ __align__(16) short wl[1536];       // bf16: w_c | w_q | w_cq
    __shared__ __align__(16) float ctl[64];

    const int bid   = blockIdx.x;
    const int b     = ((bid & 7) << 1) | (bid >> 8);   // XCD-affine batch (bijective)
    const int inner = (bid >> 3) & 31;
    const int mt    = inner >> 1;                      // 16 M-tiles of 64 rows
    const int nb    = inner & 1;                       // 2 N-halves of 64 cols
    const int tid   = threadIdx.x;
    const int lane  = tid & 63;
    const int wid   = tid >> 6;                        // 0..7
    const int wm    = wid >> 2, wn = wid & 3;          // 2x4 wave grid; wave tile 32x16
    const int rif   = lane & 15;
    const int kg    = lane >> 4;

    // ---- weights -> LDS bf16 (once; 192 threads x 8) ----
    if (tid < 192) {
        const float* s = kern + tid * 8;
        f32x4 v0 = *(const f32x4*)s;
        f32x4 v1 = *(const f32x4*)(s + 4);
        bf16x8 o;
        o[0]=f2bf(v0[0]); o[1]=f2bf(v0[1]); o[2]=f2bf(v0[2]); o[3]=f2bf(v0[3]);
        o[4]=f2bf(v1[0]); o[5]=f2bf(v1[1]); o[6]=f2bf(v1[2]); o[7]=f2bf(v1[3]);
        *(bf16x8*)&wl[tid * 8] = o;
    }

    // ---- staging: 512 threads; A row ar=tid>>3, B row bj=tid>>3, col slice (tid&7)*8 ----
    const int ar  = tid >> 3;
    const int acs = (tid & 7) * 8;
    const float* ag = c + (size_t)(b * NC_ + mt * 64 + ar) * D_ + acs;
    const int aw = ar * 128 + ((acs * 2) ^ ((ar & 7) << 4));

    const int bj  = ar;                                // same mapping for B rows
    const float* bg = q + (size_t)(b * NQ_ + nb * 64 + bj) * D_ + acs;
    const int bw = 8192 + bj * 128 + ((acs * 2) ^ ((bj & 7) << 4));

    f32x4 sa[2][2], sb[2][2];          // 2 tiles in flight, 8 floats each side
    float cta = 0.f;
    f32x4 acc00 = {}, acc10 = {};      // wave tile 32x16: 2 M-frags x 1 N-frag
    f32x4 acc_q0 = {};                 // D[i][j] = qt_j (broadcast-A MFMA, raw B)

#define ISSUE(T)                                                   \
    do { const int s_ = (T) & 1;                                   \
        sa[s_][0] = *(const f32x4*)(ag + (T) * 64);                \
        sa[s_][1] = *(const f32x4*)(ag + (T) * 64 + 4);            \
        sb[s_][0] = *(const f32x4*)(bg + (T) * 64);                \
        sb[s_][1] = *(const f32x4*)(bg + (T) * 64 + 4);            \
    } while (0)

#define WRITE(T)                                                               \
    do { const int s_ = (T) & 1; char* Lw = &lds[s_][0];                       \
        bf16x8 wcq = *(const bf16x8*)&wl[1024 + (T) * 64 + acs];               \
        bf16x8 wc8 = *(const bf16x8*)&wl[       (T) * 64 + acs];               \
        bf16x8 oa, ob;                                                         \
        _Pragma("unroll")                                                      \
        for (int e = 0; e < 8; ++e) {                                          \
            float x = sa[s_][e >> 2][e & 3];                                   \
            oa[e] = f2bf(x * bf2f(wcq[e]));                                    \
            cta += x * bf2f(wc8[e]);                                           \
            ob[e] = f2bf(sb[s_][e >> 2][e & 3]);                               \
        }                                                                      \
        *(bf16x8*)(Lw + aw) = oa;                                              \
        *(bf16x8*)(Lw + bw) = ob;                                              \
    } while (0)

#define COMPUTE(T)                                                                                   \
    do { const char* L = &lds[(T) & 1][0];                                                           \
        _Pragma("unroll")                                                                            \
        for (int kk = 0; kk < 2; ++kk) {                                                             \
            const int ks = kk * 64 + kg * 16;                                                        \
            bf16x8 af0, af1, bf0, wqf;                                                               \
            { int r = wm*32 + rif;      af0 = *(const bf16x8*)(L + r*128 + (ks ^ ((r & 7) << 4))); } \
            { int r = wm*32 + 16 + rif; af1 = *(const bf16x8*)(L + r*128 + (ks ^ ((r & 7) << 4))); } \
            { int j = wn*16 + rif;      bf0 = *(const bf16x8*)(L + 8192 + j*128 + (ks ^ ((j & 7) << 4))); } \
            wqf = *(const bf16x8*)&wl[512 + (T) * 64 + kk * 32 + kg * 8];                            \
            acc00 = __builtin_amdgcn_mfma_f32_16x16x32_bf16(af0, bf0, acc00, 0, 0, 0);               \
            acc10 = __builtin_amdgcn_mfma_f32_16x16x32_bf16(af1, bf0, acc10, 0, 0, 0);               \
            acc_q0 = __builtin_amdgcn_mfma_f32_16x16x32_bf16(wqf, bf0, acc_q0, 0, 0, 0);             \
        }                                                                                            \
    } while (0)

    // ---- prologue ----
    ISSUE(0); ISSUE(1);
    asm volatile("s_waitcnt lgkmcnt(0)" ::: "memory");
    __builtin_amdgcn_sched_barrier(0);
    __builtin_amdgcn_s_barrier();
    WRITE(0);
    asm volatile("s_waitcnt lgkmcnt(0)" ::: "memory");
    __builtin_amdgcn_sched_barrier(0);
    __builtin_amdgcn_s_barrier();

    #pragma unroll
    for (int kt = 0; kt < NKT; ++kt) {
        if (kt + 2 < NKT) ISSUE(kt + 2);
        __builtin_amdgcn_sched_barrier(0);
        COMPUTE(kt);
        if (kt + 1 < NKT) {
            WRITE(kt + 1);
            asm volatile("s_waitcnt lgkmcnt(0)" ::: "memory");
            __builtin_amdgcn_sched_barrier(0);
            __builtin_amdgcn_s_barrier();
        }
    }
#undef ISSUE
#undef WRITE
#undef COMPUTE

    // ---- ct reduction: 8 threads (tid&7) share row ar ----
    cta += __shfl_xor(cta, 1); cta += __shfl_xor(cta, 2); cta += __shfl_xor(cta, 4);
    if ((tid & 7) == 0) ctl[ar] = cta;
    asm volatile("s_waitcnt lgkmcnt(0)" ::: "memory");
    __builtin_amdgcn_sched_barrier(0);
    __builtin_amdgcn_s_barrier();

    // ---- epilogue: out = cq + ct + qt + bias ----
    const float bias = *bias_p;
    const float qt0 = acc_q0[0] + bias;     // all regs equal qt_j (j = wn*16+rif)
    #pragma unroll
    for (int mf = 0; mf < 2; ++mf) {
        f32x4 ctv = *(const f32x4*)&ctl[wm * 32 + mf * 16 + kg * 4];
        float* o = out + ((size_t)(b * NC_ + mt * 64 + wm * 32 + mf * 16 + kg * 4)) * NQ_
                 + nb * 64 + wn * 16 + rif;
        const f32x4 a0 = mf ? acc10 : acc00;
        #pragma unroll
        for (int r = 0; r < 4; ++r)
            o[(size_t)r * NQ_] = a0[r] + ctv[r] + qt0;
    }
}

extern "C" void kernel_launch(void* const* d_in, const int* in_sizes, int n_in,
                              void* d_out, int out_size, void* d_ws, size_t ws_size,
                              hipStream_t stream) {
    const float* c    = (const float*)d_in[0];
    const float* q    = (const float*)d_in[1];
    const float* kern = (const float*)d_in[2];
    const float* bias = (const float*)d_in[3];
    float* out = (float*)d_out;

    // Grid 512 blocks x 512 THREADS (launch config matches 8-wave kernel — R2 lesson).
    sim_kernel<<<512, 512, 0, stream>>>(c, q, kern, bias, out);
}